// Round 7
// baseline (47.656 us; speedup 1.0000x reference)
//
#include <hip/hip_runtime.h>
#include <hip/hip_bf16.h>

#define NN 2048   // n_nodes
#define CC 512    // channels

typedef __bf16 bf16x8 __attribute__((ext_vector_type(8)));
typedef float  f32x4  __attribute__((ext_vector_type(4)));
typedef int    i32x4  __attribute__((ext_vector_type(4)));
typedef unsigned short u16x4 __attribute__((ext_vector_type(4)));

__device__ __forceinline__ unsigned short f2bf(float f) {
    unsigned int u = __builtin_bit_cast(unsigned int, f);
    u += 0x7FFFu + ((u >> 16) & 1u);
    return (unsigned short)(u >> 16);
}
__device__ __forceinline__ float bf2f(unsigned short u) {
    unsigned int v = (unsigned int)u << 16;
    return __builtin_bit_cast(float, v);
}

// ---- fused prep:
//   blocks [0,4096): cast L->bf16, XCD-aligned (writer XCD == GEMM consumer XCD),
//                    f32 read non-temporal (streaming), Lbf store normal (L2-dirty local).
//   blocks [4096,4352): x [2048][512] -> vT bf16 [512][2048] (plain stores). ----
__global__ void prep_kernel(const float* __restrict__ L,
                            unsigned short* __restrict__ Lbf,
                            const float* __restrict__ x,
                            unsigned short* __restrict__ vbf) {
    __shared__ float tile[64][65];
    if (blockIdx.x < 4096) {
        int xcd = blockIdx.x & 7;
        int j   = blockIdx.x >> 3;               // 0..511
        int row = xcd * 256 + (j >> 1);          // rows this XCD's GEMM blocks consume
        size_t off = (size_t)row * NN + (j & 1) * 1024 + threadIdx.x * 4;
        f32x4 v = __builtin_nontemporal_load((const f32x4*)(L + off));
        u16x4 o;
        o[0] = f2bf(v[0]); o[1] = f2bf(v[1]); o[2] = f2bf(v[2]); o[3] = f2bf(v[3]);
        *(u16x4*)(Lbf + off) = o;
    } else {
        int b2 = blockIdx.x - 4096;
        int bi = b2 & 31;    // node tile
        int bc = b2 >> 5;    // channel tile
        int tid = threadIdx.x;
        #pragma unroll
        for (int rr = 0; rr < 16; ++rr) {
            int r = (tid >> 6) + rr * 4;
            int c = tid & 63;
            tile[r][c] = x[(size_t)(bi * 64 + r) * CC + bc * 64 + c];
        }
        __syncthreads();
        #pragma unroll
        for (int rr = 0; rr < 16; ++rr) {
            int cc2 = (tid >> 6) + rr * 4;
            int r   = tid & 63;
            vbf[(size_t)(bc * 64 + cc2) * NN + bi * 64 + r] = f2bf(tile[r][cc2]);
        }
    }
}

// ---- GEMM w = v @ L (L symmetric -> both operands row-read), 64x64 tile, 8 waves
//      each owning a disjoint 256-wide K-chunk. MFMA fragments loaded DIRECTLY
//      global->VGPR (no LDS in main loop: wave-split-K has zero reuse, LDS was a
//      pure bounce). 3-deep register pipeline, immediate-offset loads, no barriers.
//      LDS used only for the cross-wave reduction + epilogue staging.
//      PHASE 1: vout = bf16(w)                        (w = xT*L, raw)
//      PHASE 2: out[n][c] = c0*x + c1t*w1 + c2t^2*w2  (LDS-staged coalesced) ----
template <int PHASE>
__global__ __launch_bounds__(512)
void gemm_step_kernel(const unsigned short* __restrict__ A,   // [512][2048] bf16 (phase2: w1bf)
                      const unsigned short* __restrict__ Lb,  // [2048][2048] bf16
                      const float* __restrict__ xin,          // x [2048][512] f32 (phase2)
                      unsigned short* __restrict__ vout,      // [512][2048] bf16 (phase1)
                      float* __restrict__ out,                // [2048][512] f32 (phase2)
                      const float* __restrict__ tptr) {
    __shared__ float scr[8 * 4096];   // 128 KB (reduction scratch / epilogue tile)

    const int tid  = threadIdx.x;
    const int lane = tid & 63;
    const int wid  = tid >> 6;          // 0..7

    // XCD swizzle (grid 256 = 8 m-tiles x 32 n-tiles)
    const int bid = blockIdx.x;
    const int xcd = bid & 7, idx = bid >> 3;
    const int n0  = (xcd * 4 + (idx & 3)) * 64;   // node dim
    const int m0  = (idx >> 2) * 64;              // channel dim

    const int kw = wid * 256;           // this wave's K-chunk base

    // per-lane fragment base addresses (loop-invariant; k-step via imm offset i*64B)
    const unsigned short* baseA[4];
    const unsigned short* baseB[4];
    #pragma unroll
    for (int f = 0; f < 4; ++f) {
        const int r    = f * 16 + (lane & 15);
        const int kofs = kw + (lane >> 4) * 8;
        baseA[f] = A  + (size_t)(m0 + r) * NN + kofs;
        baseB[f] = Lb + (size_t)(n0 + r) * NN + kofs;
    }

    i32x4 fa[3][4], fb[3][4];
    #pragma unroll
    for (int p = 0; p < 3; ++p)
        #pragma unroll
        for (int f = 0; f < 4; ++f) {
            fa[p][f] = *(const i32x4*)(baseA[f] + p * 32);
            fb[p][f] = *(const i32x4*)(baseB[f] + p * 32);
        }

    f32x4 acc[4][4] = {};

    #pragma unroll
    for (int i = 0; i < 8; ++i) {
        const int s = i % 3;            // static after unroll
        __builtin_amdgcn_s_setprio(1);
        #pragma unroll
        for (int fm = 0; fm < 4; ++fm)
            #pragma unroll
            for (int fn = 0; fn < 4; ++fn)
                acc[fm][fn] = __builtin_amdgcn_mfma_f32_16x16x32_bf16(
                    __builtin_bit_cast(bf16x8, fa[s][fm]),
                    __builtin_bit_cast(bf16x8, fb[s][fn]),
                    acc[fm][fn], 0, 0, 0);
        __builtin_amdgcn_s_setprio(0);
        if (i < 5) {                    // prefetch k-step i+3 into the slot just consumed
            #pragma unroll
            for (int f = 0; f < 4; ++f) {
                fa[s][f] = *(const i32x4*)(baseA[f] + (i + 3) * 32);
                fb[s][f] = *(const i32x4*)(baseB[f] + (i + 3) * 32);
            }
        }
    }

    // ---- cross-wave reduction through LDS ----
    #pragma unroll
    for (int fm = 0; fm < 4; ++fm)
        #pragma unroll
        for (int fn = 0; fn < 4; ++fn)
            *(f32x4*)(scr + wid * 4096 + (fm * 4 + fn) * 256 + lane * 4) = acc[fm][fn];
    __syncthreads();

    // wave W reduces fragment-chunks j = W and j = W+8 across all 8 partials
    f32x4 ss[2] = {};
    #pragma unroll
    for (int h = 0; h < 2; ++h)
        #pragma unroll
        for (int w = 0; w < 8; ++w)
            ss[h] += *(const f32x4*)(scr + w * 4096 + (wid + h * 8) * 256 + lane * 4);

    if (PHASE == 1) {
        // C/D layout: col = lane&15, row = (lane>>4)*4 + reg
        #pragma unroll
        for (int h = 0; h < 2; ++h) {
            int j  = wid + h * 8;
            int fm = j >> 2, fn = j & 3;
            int mb = m0 + fm * 16 + ((lane >> 4) << 2);
            int n  = n0 + fn * 16 + (lane & 15);
            #pragma unroll
            for (int r = 0; r < 4; ++r)
                vout[(size_t)(mb + r) * NN + n] = f2bf(ss[h][r]);
        }
    } else {
        // degree-2 Chebyshev-node interpolation of exp(-s) on [0, 0.42*t]
        float tt = fmaxf(tptr[0], 1e-8f);
        float T  = 0.42f * tt;
        float c0, c1, c2;
        if (T < 1e-3f) { c0 = 1.0f; c1 = -1.0f; c2 = 0.5f; }
        else {
            float sa = T * 0.9330127f, sm = T * 0.5f, sc = T * 0.0669873f;
            float fa_ = __expf(-sa), fm_ = __expf(-sm), fc = __expf(-sc);
            float d01  = (fa_ - fm_) / (sa - sm);
            float d12  = (fm_ - fc) / (sm - sc);
            float d012 = (d01 - d12) / (sa - sc);
            c2 = d012;
            c1 = d01 - d012 * (sa + sm);
            c0 = fa_ - d01 * sa + d012 * sa * sm;
        }
        const float C1 = c1 * tt;
        const float C2 = c2 * tt * tt;

        // stage C1*w1 + C2*w2 in LDS (transposed), add c0*x at coalesced write time
        float (*ot)[68] = (float (*)[68])scr;   // 64*68*4 = 17.4 KB
        __syncthreads();                        // all reduction reads of scr done
        #pragma unroll
        for (int h = 0; h < 2; ++h) {
            int j   = wid + h * 8;
            int fm  = j >> 2, fn = j & 3;
            int m_l = fm * 16 + ((lane >> 4) << 2);
            int n_l = fn * 16 + (lane & 15);
            size_t abase = (size_t)(m0 + m_l) * NN + (n0 + n_l);
            #pragma unroll
            for (int r = 0; r < 4; ++r)
                ot[n_l][m_l + r] = C1 * bf2f(A[abase + (size_t)r * NN]) + C2 * ss[h][r];
        }
        __syncthreads();
        #pragma unroll
        for (int rr = 0; rr < 2; ++rr) {
            int e    = rr * 512 + tid;          // 1024 f32x4 = 4096 floats
            int nloc = e >> 4, mq = e & 15;
            f32x4 v  = *(const f32x4*)&ot[nloc][mq * 4];
            f32x4 xv = *(const f32x4*)(xin + (size_t)(n0 + nloc) * CC + m0 + mq * 4);
            #pragma unroll
            for (int q = 0; q < 4; ++q) v[q] += c0 * xv[q];
            *(f32x4*)(out + (size_t)(n0 + nloc) * CC + m0 + mq * 4) = v;
        }
    }
}

extern "C" void kernel_launch(void* const* d_in, const int* in_sizes, int n_in,
                              void* d_out, int out_size, void* d_ws, size_t ws_size,
                              hipStream_t stream) {
    (void)in_sizes; (void)n_in; (void)out_size; (void)ws_size;
    const float* x = (const float*)d_in[0];
    const float* L = (const float*)d_in[1];
    const float* t = (const float*)d_in[2];
    float* out = (float*)d_out;

    char* ws = (char*)d_ws;
    unsigned short* Lbf  = (unsigned short*)ws;                   // 8 MB
    unsigned short* vA   = (unsigned short*)(ws + (8  << 20));    // 2 MB  bf16(xT)
    unsigned short* w1bf = (unsigned short*)(ws + (10 << 20));    // 2 MB  bf16(xT*L)

    prep_kernel<<<4096 + 256, 256, 0, stream>>>(L, Lbf, x, vA);
    gemm_step_kernel<1><<<256, 512, 0, stream>>>(vA,   Lbf, nullptr, w1bf, nullptr, t);
    gemm_step_kernel<2><<<256, 512, 0, stream>>>(w1bf, Lbf, x,       nullptr, out,  t);
}

// Round 8
// 41.120 us; speedup vs baseline: 1.1589x; 1.1589x over previous
//
#include <hip/hip_runtime.h>
#include <hip/hip_bf16.h>

#define NN 2048   // n_nodes
#define CC 512    // channels

typedef __bf16 bf16x8 __attribute__((ext_vector_type(8)));
typedef float  f32x4  __attribute__((ext_vector_type(4)));
typedef int    i32x4  __attribute__((ext_vector_type(4)));
typedef unsigned short u16x4 __attribute__((ext_vector_type(4)));

#define GLD_LDS16(gptr, lptr)                                                        \
    __builtin_amdgcn_global_load_lds(                                                \
        (const __attribute__((address_space(1))) void*)(gptr),                       \
        (__attribute__((address_space(3))) void*)(lptr), 16, 0, 0)

__device__ __forceinline__ unsigned short f2bf(float f) {
    unsigned int u = __builtin_bit_cast(unsigned int, f);
    u += 0x7FFFu + ((u >> 16) & 1u);
    return (unsigned short)(u >> 16);
}
__device__ __forceinline__ float bf2f(unsigned short u) {
    unsigned int v = (unsigned int)u << 16;
    return __builtin_bit_cast(float, v);
}

// ---- fused prep (unchanged from round 5/6 structure):
//   blocks [0,4096): cast L->bf16, XCD-aligned (writer XCD == GEMM consumer XCD).
//   blocks [4096,4352): x [2048][512] -> vT bf16 [512][2048]. ----
__global__ void prep_kernel(const float* __restrict__ L,
                            unsigned short* __restrict__ Lbf,
                            const float* __restrict__ x,
                            unsigned short* __restrict__ vbf) {
    __shared__ float tile[64][65];
    if (blockIdx.x < 4096) {
        int xcd = blockIdx.x & 7;
        int j   = blockIdx.x >> 3;
        int row = xcd * 256 + (j >> 1);
        size_t off = (size_t)row * NN + (j & 1) * 1024 + threadIdx.x * 4;
        f32x4 v = __builtin_nontemporal_load((const f32x4*)(L + off));
        u16x4 o;
        o[0] = f2bf(v[0]); o[1] = f2bf(v[1]); o[2] = f2bf(v[2]); o[3] = f2bf(v[3]);
        *(u16x4*)(Lbf + off) = o;
    } else {
        int b2 = blockIdx.x - 4096;
        int bi = b2 & 31;
        int bc = b2 >> 5;
        int tid = threadIdx.x;
        #pragma unroll
        for (int rr = 0; rr < 16; ++rr) {
            int r = (tid >> 6) + rr * 4;
            int c = tid & 63;
            tile[r][c] = x[(size_t)(bi * 64 + r) * CC + bc * 64 + c];
        }
        __syncthreads();
        #pragma unroll
        for (int rr = 0; rr < 16; ++rr) {
            int cc2 = (tid >> 6) + rr * 4;
            int r   = tid & 63;
            vbf[(size_t)(bc * 64 + cc2) * NN + bi * 64 + r] = f2bf(tile[r][cc2]);
        }
    }
}

// ---- GEMM w = v @ L (L symmetric -> both operands row-read), 64x64 tile, 8 waves
//      each owning a disjoint 256-wide K-chunk (8 iters of BK=32).
//      A: persistent VGPR fragments (2 generations of 16 bulk loads).
//      B: 4-deep per-wave LDS double... quad-buffer via global_load_lds,
//         counted vmcnt, ds_read pipelined one iter ahead (lgkm hidden).
//      Zero barriers in main loop; LDS reused for cross-wave reduction.
//      PHASE 1: vout = bf16(w)
//      PHASE 2: out[n][c] = c0*x + c1t*w1 + c2t^2*w2 (LDS-staged coalesced) ----
template <int PHASE>
__global__ __launch_bounds__(512)
void gemm_step_kernel(const unsigned short* __restrict__ A,   // [512][2048] bf16 (phase2: w1bf)
                      const unsigned short* __restrict__ Lb,  // [2048][2048] bf16
                      const float* __restrict__ xin,          // x [2048][512] f32 (phase2)
                      unsigned short* __restrict__ vout,      // [512][2048] bf16 (phase1)
                      float* __restrict__ out,                // [2048][512] f32 (phase2)
                      const float* __restrict__ tptr) {
    __shared__ short lds[65536];   // 128 KB: 8 waves x 4 B-bufs x 4KB; reused for reduction

    const int tid  = threadIdx.x;
    const int lane = tid & 63;
    const int wid  = tid >> 6;          // 0..7

    // XCD swizzle (grid 256 = 8 m-tiles x 32 n-tiles)
    const int bid = blockIdx.x;
    const int xcd = bid & 7, idx = bid >> 3;
    const int n0  = (xcd * 4 + (idx & 3)) * 64;   // node dim
    const int m0  = (idx >> 2) * 64;              // channel dim

    short* wbase = lds + wid * 8192;    // this wave's 16KB (4 bufs x 2048 shorts)
    const int kw = wid * 256;           // this wave's K-chunk base

    // ---- B staging (same swizzle as round 5: granule (row,slot) holds kb=(slot-(row>>1))&3)
    const unsigned short* pB[4];
    #pragma unroll
    for (int i = 0; i < 4; ++i) {
        int row = i * 16 + (lane >> 2);
        int kb  = ((lane & 3) - (row >> 1)) & 3;
        pB[i] = Lb + (size_t)(n0 + row) * NN + kw + kb * 8;
    }
    auto stage = [&](int kt) {   // 4 gld_lds into buf[kt&3]
        short* d = wbase + (kt & 3) * 2048;
        #pragma unroll
        for (int i = 0; i < 4; ++i)
            GLD_LDS16(pB[i] + kt * 32, d + i * 512);
    };

    // ---- A fragment addresses (persistent regs; k-step via imm offset)
    const unsigned short* baseA[4];
    #pragma unroll
    for (int f = 0; f < 4; ++f)
        baseA[f] = A + (size_t)(m0 + f * 16 + (lane & 15)) * NN + kw + (lane >> 4) * 8;

    i32x4 a0[4][4], a1[4][4];     // generations: iters 0-3 / 4-7
    i32x4 bfr[2][4];              // B-frag double buffer
    f32x4 acc[4][4] = {};

    auto dsread = [&](int kt, int slot_sel) {
        const short* sb = wbase + (kt & 3) * 2048;
        #pragma unroll
        for (int f = 0; f < 4; ++f) {
            int row  = f * 16 + (lane & 15);
            int slot = ((lane >> 4) + (row >> 1)) & 3;
            bfr[slot_sel][f] = *(const i32x4*)(sb + (row * 4 + slot) * 8);
        }
    };

    // ---- prologue: A gen0 (16 loads), stage bufs 0..2 (12 loads)
    #pragma unroll
    for (int p = 0; p < 4; ++p)
        #pragma unroll
        for (int f = 0; f < 4; ++f)
            a0[p][f] = *(const i32x4*)(baseA[f] + p * 32);
    stage(0); stage(1); stage(2);
    asm volatile("s_waitcnt vmcnt(8)" ::: "memory");   // A0 + buf0 done
    dsread(0, 0);

    #pragma unroll
    for (int i = 0; i < 8; ++i) {
        asm volatile("s_waitcnt lgkmcnt(0)" ::: "memory");   // frags for iter i ready
        if (i < 5) stage(i + 3);
        if (i == 2) {                                        // A gen1 (16 loads)
            #pragma unroll
            for (int p = 0; p < 4; ++p)
                #pragma unroll
                for (int f = 0; f < 4; ++f)
                    a1[p][f] = *(const i32x4*)(baseA[f] + (p + 4) * 32);
        }
        // counted vmcnt: completes buf[i+1] (and A gen1 by iter 4)
        if (i == 0 || i == 1)      asm volatile("s_waitcnt vmcnt(8)"  ::: "memory");
        else if (i == 2 || i == 3) asm volatile("s_waitcnt vmcnt(24)" ::: "memory");
        else if (i == 4)           asm volatile("s_waitcnt vmcnt(8)"  ::: "memory");
        else if (i == 5)           asm volatile("s_waitcnt vmcnt(4)"  ::: "memory");
        else if (i == 6)           asm volatile("s_waitcnt vmcnt(0)"  ::: "memory");
        if (i < 7) dsread(i + 1, (i + 1) & 1);               // pipelined one iter ahead

        __builtin_amdgcn_s_setprio(1);
        #pragma unroll
        for (int fm = 0; fm < 4; ++fm)
            #pragma unroll
            for (int fn = 0; fn < 4; ++fn)
                acc[fm][fn] = __builtin_amdgcn_mfma_f32_16x16x32_bf16(
                    __builtin_bit_cast(bf16x8, (i < 4) ? a0[i][fm] : a1[i - 4][fm]),
                    __builtin_bit_cast(bf16x8, bfr[i & 1][fn]),
                    acc[fm][fn], 0, 0, 0);
        __builtin_amdgcn_s_setprio(0);
    }

    // ---- cross-wave reduction through (reused, wave-private-then-shared) LDS ----
    float* scr = (float*)lds;
    #pragma unroll
    for (int fm = 0; fm < 4; ++fm)
        #pragma unroll
        for (int fn = 0; fn < 4; ++fn)
            *(f32x4*)(scr + wid * 4096 + (fm * 4 + fn) * 256 + lane * 4) = acc[fm][fn];
    __syncthreads();

    f32x4 ss[2] = {};
    #pragma unroll
    for (int h = 0; h < 2; ++h)
        #pragma unroll
        for (int w = 0; w < 8; ++w)
            ss[h] += *(const f32x4*)(scr + w * 4096 + (wid + h * 8) * 256 + lane * 4);

    if (PHASE == 1) {
        // C/D layout: col = lane&15, row = (lane>>4)*4 + reg
        #pragma unroll
        for (int h = 0; h < 2; ++h) {
            int j  = wid + h * 8;
            int fm = j >> 2, fn = j & 3;
            int mb = m0 + fm * 16 + ((lane >> 4) << 2);
            int n  = n0 + fn * 16 + (lane & 15);
            #pragma unroll
            for (int r = 0; r < 4; ++r)
                vout[(size_t)(mb + r) * NN + n] = f2bf(ss[h][r]);
        }
    } else {
        // degree-2 Chebyshev-node interpolation of exp(-s) on [0, 0.42*t]
        float tt = fmaxf(tptr[0], 1e-8f);
        float T  = 0.42f * tt;
        float c0, c1, c2;
        if (T < 1e-3f) { c0 = 1.0f; c1 = -1.0f; c2 = 0.5f; }
        else {
            float sa = T * 0.9330127f, sm = T * 0.5f, sc = T * 0.0669873f;
            float fa_ = __expf(-sa), fm_ = __expf(-sm), fc = __expf(-sc);
            float d01  = (fa_ - fm_) / (sa - sm);
            float d12  = (fm_ - fc) / (sm - sc);
            float d012 = (d01 - d12) / (sa - sc);
            c2 = d012;
            c1 = d01 - d012 * (sa + sm);
            c0 = fa_ - d01 * sa + d012 * sa * sm;
        }
        const float C1 = c1 * tt;
        const float C2 = c2 * tt * tt;

        // stage C1*w1 + C2*w2 in LDS (transposed), add c0*x at coalesced write
        float (*ot)[68] = (float (*)[68])scr;   // 64*68*4 = 17.4 KB
        __syncthreads();                        // all reduction reads of scr done
        #pragma unroll
        for (int h = 0; h < 2; ++h) {
            int j   = wid + h * 8;
            int fm  = j >> 2, fn = j & 3;
            int m_l = fm * 16 + ((lane >> 4) << 2);
            int n_l = fn * 16 + (lane & 15);
            size_t abase = (size_t)(m0 + m_l) * NN + (n0 + n_l);
            #pragma unroll
            for (int r = 0; r < 4; ++r)
                ot[n_l][m_l + r] = C1 * bf2f(A[abase + (size_t)r * NN]) + C2 * ss[h][r];
        }
        __syncthreads();
        #pragma unroll
        for (int rr = 0; rr < 2; ++rr) {
            int e    = rr * 512 + tid;
            int nloc = e >> 4, mq = e & 15;
            f32x4 v  = *(const f32x4*)&ot[nloc][mq * 4];
            f32x4 xv = *(const f32x4*)(xin + (size_t)(n0 + nloc) * CC + m0 + mq * 4);
            #pragma unroll
            for (int q = 0; q < 4; ++q) v[q] += c0 * xv[q];
            *(f32x4*)(out + (size_t)(n0 + nloc) * CC + m0 + mq * 4) = v;
        }
    }
}

extern "C" void kernel_launch(void* const* d_in, const int* in_sizes, int n_in,
                              void* d_out, int out_size, void* d_ws, size_t ws_size,
                              hipStream_t stream) {
    (void)in_sizes; (void)n_in; (void)out_size; (void)ws_size;
    const float* x = (const float*)d_in[0];
    const float* L = (const float*)d_in[1];
    const float* t = (const float*)d_in[2];
    float* out = (float*)d_out;

    char* ws = (char*)d_ws;
    unsigned short* Lbf  = (unsigned short*)ws;                   // 8 MB
    unsigned short* vA   = (unsigned short*)(ws + (8  << 20));    // 2 MB  bf16(xT)
    unsigned short* w1bf = (unsigned short*)(ws + (10 << 20));    // 2 MB  bf16(xT*L)

    prep_kernel<<<4096 + 256, 256, 0, stream>>>(L, Lbf, x, vA);
    gemm_step_kernel<1><<<256, 512, 0, stream>>>(vA,   Lbf, nullptr, w1bf, nullptr, t);
    gemm_step_kernel<2><<<256, 512, 0, stream>>>(w1bf, Lbf, x,       nullptr, out,  t);
}

// Round 9
// 30.065 us; speedup vs baseline: 1.5851x; 1.3677x over previous
//
#include <hip/hip_runtime.h>
#include <hip/hip_bf16.h>

#define NN 2048   // n_nodes
#define CC 512    // channels

typedef __bf16 bf16x8 __attribute__((ext_vector_type(8)));
typedef float  f32x4  __attribute__((ext_vector_type(4)));
typedef int    i32x4  __attribute__((ext_vector_type(4)));
typedef unsigned short u16x4 __attribute__((ext_vector_type(4)));

#define GLD_LDS16(gptr, lptr)                                                        \
    __builtin_amdgcn_global_load_lds(                                                \
        (const __attribute__((address_space(1))) void*)(gptr),                       \
        (__attribute__((address_space(3))) void*)(lptr), 16, 0, 0)

__device__ __forceinline__ unsigned short f2bf(float f) {
    unsigned int u = __builtin_bit_cast(unsigned int, f);
    u += 0x7FFFu + ((u >> 16) & 1u);
    return (unsigned short)(u >> 16);
}
__device__ __forceinline__ float bf2f(unsigned short u) {
    unsigned int v = (unsigned int)u << 16;
    return __builtin_bit_cast(float, v);
}

// Packed operand layout = exact LDS image the GEMM consumes:
//   pack[tile][w:8][kt:8][granule:256][8 shorts],  granule = row*4 + slot,
//   content(row,slot,e) = M[tile*64+row][w*256 + kt*32 + kb*8 + e],  kb = (slot-(row>>1))&3.
// Element (tile, row, kglob) lives at:
__device__ __forceinline__ size_t pack_addr(int tile, int row, int kglob) {
    int w    = kglob >> 8;
    int kt   = (kglob >> 5) & 7;
    int kb   = (kglob >> 3) & 3;
    int slot = (kb + (row >> 1)) & 3;
    return ((size_t)(tile * 8 + w) * 8 + kt) * 2048 + (size_t)(row * 4 + slot) * 8 + (kglob & 7);
}

// ---- prep: blocks [0,256): L f32 -> Lpack (one block per (nt,w), XCD-aligned so
//            writer XCD == consumer XCD). blocks [256,320): x -> Apack (xT packed).
__global__ __launch_bounds__(256)
void prep_kernel(const float* __restrict__ L, unsigned short* __restrict__ Lpack,
                 const float* __restrict__ x, unsigned short* __restrict__ Apack) {
    __shared__ unsigned short sbuf[256 * 72];   // 36 KB, aliased by both branches
    const int tid = threadIdx.x;
    if (blockIdx.x < 256) {
        // GEMM block with n-tile nt runs on XCD nt>>2 -> place this block there too.
        unsigned short (*tile)[264] = (unsigned short(*)[264])sbuf;   // 64 x 264 (row stride 528B, 16B-mult)
        int j  = blockIdx.x >> 3;
        int nt = (blockIdx.x & 7) * 4 + (j & 3);
        int w  = j >> 2;
        #pragma unroll
        for (int it = 0; it < 16; ++it) {       // wave reads one full 1KB row-chunk
            int r = it * 4 + (tid >> 6);
            int c = (tid & 63) * 4;
            f32x4 v = __builtin_nontemporal_load(
                (const f32x4*)(L + (size_t)(nt * 64 + r) * NN + w * 256 + c));
            u16x4 o;
            o[0] = f2bf(v[0]); o[1] = f2bf(v[1]); o[2] = f2bf(v[2]); o[3] = f2bf(v[3]);
            *(u16x4*)&tile[r][c] = o;
        }
        __syncthreads();
        unsigned short* outp = Lpack + (size_t)(nt * 8 + w) * 8 * 2048;
        int row = tid >> 2, slot = tid & 3;
        int kb  = (slot - (row >> 1)) & 3;
        #pragma unroll
        for (int kt = 0; kt < 8; ++kt) {
            i32x4 v = *(const i32x4*)&tile[row][kt * 32 + kb * 8];
            *(i32x4*)(outp + kt * 2048 + tid * 8) = v;   // fully contiguous 16B/thread
        }
    } else {
        unsigned short (*t2)[72] = (unsigned short(*)[72])sbuf;       // 256 x 72 (stride 144B, 16B-mult)
        int b2 = blockIdx.x - 256;
        int mt = b2 >> 3, w = b2 & 7;
        #pragma unroll
        for (int it = 0; it < 16; ++it) {
            int r = it * 16 + (tid >> 4);       // k-local node row
            int c = (tid & 15) * 4;             // m-local channel
            f32x4 v = *(const f32x4*)(x + (size_t)(w * 256 + r) * CC + mt * 64 + c);
            t2[r][c] = f2bf(v[0]); t2[r][c + 1] = f2bf(v[1]);
            t2[r][c + 2] = f2bf(v[2]); t2[r][c + 3] = f2bf(v[3]);
        }
        __syncthreads();
        unsigned short* outp = Apack + (size_t)(mt * 8 + w) * 8 * 2048;
        int row = tid >> 2, slot = tid & 3;     // row = m-local
        int kb  = (slot - (row >> 1)) & 3;
        #pragma unroll
        for (int kt = 0; kt < 8; ++kt) {
            unsigned short tmp[8];
            #pragma unroll
            for (int e = 0; e < 8; ++e) tmp[e] = t2[kt * 32 + kb * 8 + e][row];
            *(i32x4*)(outp + kt * 2048 + tid * 8) = *(const i32x4*)tmp;
        }
    }
}

// ---- GEMM w = v @ L (L symmetric -> row-read both), 64x64 tile, 8 waves with
//      disjoint 256-wide K-chunks. BOTH operands pre-packed -> every
//      global_load_lds is 1KB CONTIGUOUS (kills the 16-segment VMEM scatter that
//      plateaued R5/R7/R8 at ~13us/GEMM). Per-wave 2-deep A+B LDS double buffer,
//      counted vmcnt, zero barriers in main loop; cross-wave reduction in LDS.
//      PHASE 1: w1pack = bf16(w)  (packed layout, consumed by GEMM2)
//      PHASE 2: out[n][c] = c0*x + C1*w1 + C2*w2  (LDS-staged coalesced) ----
template <int PHASE>
__global__ __launch_bounds__(512)
void gemm_step_kernel(const unsigned short* __restrict__ Apk,  // packed A  [8][8][8][2048]
                      const unsigned short* __restrict__ Bpk,  // packed L  [32][8][8][2048]
                      const float* __restrict__ xin,           // x [2048][512] (phase2)
                      unsigned short* __restrict__ w1pk,       // packed w1 out (phase1)
                      float* __restrict__ out,                 // [2048][512] (phase2)
                      const float* __restrict__ tptr) {
    __shared__ short lds[65536];   // 128 KB: 8 waves x 2 bufs x (A 4KB + B 4KB); reused for reduction

    const int tid  = threadIdx.x;
    const int lane = tid & 63;
    const int wid  = tid >> 6;

    const int bid = blockIdx.x;
    const int xcd = bid & 7, idx = bid >> 3;
    const int n0  = (xcd * 4 + (idx & 3)) * 64;
    const int m0  = (idx >> 2) * 64;
    const int mt  = m0 >> 6, nt = n0 >> 6;

    short* wbase = lds + wid * 8192;    // this wave's 16KB
    const unsigned short* SA = Apk + (size_t)(mt * 8 + wid) * 8 * 2048 + lane * 8;
    const unsigned short* SB = Bpk + (size_t)(nt * 8 + wid) * 8 * 2048 + lane * 8;

    auto stage = [&](int kt) {          // 8 instrs, each 1KB contiguous
        short* d = wbase + (kt & 1) * 4096;
        #pragma unroll
        for (int i = 0; i < 4; ++i) {
            GLD_LDS16(SA + kt * 2048 + i * 512, d + i * 512);
            GLD_LDS16(SB + kt * 2048 + i * 512, d + 2048 + i * 512);
        }
    };

    i32x4 af[4], bfv[4];
    f32x4 acc[4][4] = {};

    stage(0); stage(1);
    #pragma unroll
    for (int i = 0; i < 8; ++i) {
        if (i < 7) asm volatile("s_waitcnt vmcnt(8)" ::: "memory");
        else       asm volatile("s_waitcnt vmcnt(0)" ::: "memory");
        const short* s = wbase + (i & 1) * 4096;
        #pragma unroll
        for (int f = 0; f < 4; ++f) {
            int row  = f * 16 + (lane & 15);
            int slot = ((lane >> 4) + (row >> 1)) & 3;
            int g    = row * 4 + slot;
            af[f]  = *(const i32x4*)(s + g * 8);
            bfv[f] = *(const i32x4*)(s + 2048 + g * 8);
        }
        asm volatile("s_waitcnt lgkmcnt(0)" ::: "memory");   // frags in regs -> WAR-safe restage
        if (i < 6) stage(i + 2);

        __builtin_amdgcn_s_setprio(1);
        #pragma unroll
        for (int fm = 0; fm < 4; ++fm)
            #pragma unroll
            for (int fn = 0; fn < 4; ++fn)
                acc[fm][fn] = __builtin_amdgcn_mfma_f32_16x16x32_bf16(
                    __builtin_bit_cast(bf16x8, af[fm]),
                    __builtin_bit_cast(bf16x8, bfv[fn]),
                    acc[fm][fn], 0, 0, 0);
        __builtin_amdgcn_s_setprio(0);
    }

    // ---- cross-wave reduction through (reused) LDS; wave w's scr region == its staging region
    float* scr = (float*)lds;
    #pragma unroll
    for (int fm = 0; fm < 4; ++fm)
        #pragma unroll
        for (int fn = 0; fn < 4; ++fn)
            *(f32x4*)(scr + wid * 4096 + (fm * 4 + fn) * 256 + lane * 4) = acc[fm][fn];
    __syncthreads();

    f32x4 ss[2] = {};
    #pragma unroll
    for (int h = 0; h < 2; ++h)
        #pragma unroll
        for (int w = 0; w < 8; ++w)
            ss[h] += *(const f32x4*)(scr + w * 4096 + (wid + h * 8) * 256 + lane * 4);

    if (PHASE == 1) {
        // C/D layout: col = lane&15, row = (lane>>4)*4 + reg. Write packed for GEMM2.
        #pragma unroll
        for (int h = 0; h < 2; ++h) {
            int j   = wid + h * 8;
            int fm  = j >> 2, fn = j & 3;
            int m_l = fm * 16 + ((lane >> 4) << 2);
            int n_l = fn * 16 + (lane & 15);
            #pragma unroll
            for (int r = 0; r < 4; ++r)
                w1pk[pack_addr(mt, m_l + r, n0 + n_l)] = f2bf(ss[h][r]);
        }
    } else {
        // degree-2 Chebyshev-node interpolation of exp(-s) on [0, 0.42*t]
        float tt = fmaxf(tptr[0], 1e-8f);
        float T  = 0.42f * tt;
        float c0, c1, c2;
        if (T < 1e-3f) { c0 = 1.0f; c1 = -1.0f; c2 = 0.5f; }
        else {
            float sa = T * 0.9330127f, sm = T * 0.5f, sc = T * 0.0669873f;
            float fa_ = __expf(-sa), fm_ = __expf(-sm), fc = __expf(-sc);
            float d01  = (fa_ - fm_) / (sa - sm);
            float d12  = (fm_ - fc) / (sm - sc);
            float d012 = (d01 - d12) / (sa - sc);
            c2 = d012;
            c1 = d01 - d012 * (sa + sm);
            c0 = fa_ - d01 * sa + d012 * sa * sm;
        }
        const float C1 = c1 * tt;
        const float C2 = c2 * tt * tt;

        float (*ot)[68] = (float (*)[68])scr;   // 64x68 f32 = 17.4 KB
        __syncthreads();                        // all reduction reads of scr done
        #pragma unroll
        for (int h = 0; h < 2; ++h) {
            int j   = wid + h * 8;
            int fm  = j >> 2, fn = j & 3;
            int m_l = fm * 16 + ((lane >> 4) << 2);
            int n_l = fn * 16 + (lane & 15);
            #pragma unroll
            for (int r = 0; r < 4; ++r)
                ot[n_l][m_l + r] = C1 * bf2f(Apk[pack_addr(mt, m_l + r, n0 + n_l)])
                                 + C2 * ss[h][r];
        }
        __syncthreads();
        #pragma unroll
        for (int rr = 0; rr < 2; ++rr) {
            int e    = rr * 512 + tid;
            int nloc = e >> 4, mq = e & 15;
            f32x4 v  = *(const f32x4*)&ot[nloc][mq * 4];
            f32x4 xv = *(const f32x4*)(xin + (size_t)(n0 + nloc) * CC + m0 + mq * 4);
            #pragma unroll
            for (int q = 0; q < 4; ++q) v[q] += c0 * xv[q];
            *(f32x4*)(out + (size_t)(n0 + nloc) * CC + m0 + mq * 4) = v;
        }
    }
}

extern "C" void kernel_launch(void* const* d_in, const int* in_sizes, int n_in,
                              void* d_out, int out_size, void* d_ws, size_t ws_size,
                              hipStream_t stream) {
    (void)in_sizes; (void)n_in; (void)out_size; (void)ws_size;
    const float* x = (const float*)d_in[0];
    const float* L = (const float*)d_in[1];
    const float* t = (const float*)d_in[2];
    float* out = (float*)d_out;

    char* ws = (char*)d_ws;
    unsigned short* Lpack = (unsigned short*)ws;                   // 8 MB  packed L
    unsigned short* Apk1  = (unsigned short*)(ws + (8  << 20));    // 2 MB  packed bf16 xT
    unsigned short* w1pk  = (unsigned short*)(ws + (10 << 20));    // 2 MB  packed bf16 w1

    prep_kernel<<<320, 256, 0, stream>>>(L, Lpack, x, Apk1);
    gemm_step_kernel<1><<<256, 512, 0, stream>>>(Apk1, Lpack, nullptr, w1pk, nullptr, t);
    gemm_step_kernel<2><<<256, 512, 0, stream>>>(w1pk, Lpack, x,       nullptr, out,  t);
}